// Round 16
// baseline (164.528 us; speedup 1.0000x reference)
//
#include <hip/hip_runtime.h>
#include <math.h>

#define Bsz 1024
#define Din 512
#define Hdim 1024
#define Aact 64
#define MAXT 23   // max row-tiles across experts: 7 partial + 16
#define NXCD 8

// out layout (float32): option_probs[1024*8] | action_probs[1024*64] | term[1024] | opt_argmax[1024] | sel_action[1024]
#define OFF_ACT   8192
#define OFF_TERM  73728
#define OFF_OARG  74752
#define OFF_SACT  75776

// ---------------- threefry2x32-20, key (0,42), partitionable XOR-fold (verified R3-R15) ----------------
__device__ __forceinline__ unsigned rotl32(unsigned x, int d){ return (x << d) | (x >> (32 - d)); }

__device__ __forceinline__ void threefry_042(unsigned& x0, unsigned& x1){
  const unsigned ks0 = 0u, ks1 = 42u, ks2 = 0x1BD11BDAu ^ 0u ^ 42u;
  x0 += ks0; x1 += ks1;
#define TFR(r) { x0 += x1; x1 = rotl32(x1, r); x1 ^= x0; }
  TFR(13) TFR(15) TFR(26) TFR(6)  x0 += ks1; x1 += ks2 + 1u;
  TFR(17) TFR(29) TFR(16) TFR(24) x0 += ks2; x1 += ks0 + 2u;
  TFR(13) TFR(15) TFR(26) TFR(6)  x0 += ks0; x1 += ks1 + 3u;
  TFR(17) TFR(29) TFR(16) TFR(24) x0 += ks1; x1 += ks2 + 4u;
  TFR(13) TFR(15) TFR(26) TFR(6)  x0 += ks2; x1 += ks0 + 5u;
#undef TFR
}

__device__ __forceinline__ float gumbel_at(int idx){
  unsigned x0 = 0u, x1 = (unsigned)idx;
  threefry_042(x0, x1);
  unsigned bits = x0 ^ x1;
  float f = __uint_as_float((bits >> 9) | 0x3F800000u) - 1.0f;
  float u = fmaxf(f, 1.1754944e-38f);
  return -logf(-logf(u));
}

// ---------------- 64x64 tile GEMM, 4 waves in-block split-K x GLOBAL split-K x2, 8x8/thread ----------
// R16 = R15's proven body + blockIdx.z-encoded global K-split (kb): kb=0 -> raw sums to C,
// kb=1 -> partial buffer P; bias+relu moved to reduce_relu. Rationale: R11->R15 showed block-level
// TLP (not loop microstructure) is the lever; dense now 1024 blocks = exactly 4/CU (16 waves/CU),
// grouped 736; per-wave chain NT halves (dense/L1: 8, L2: 16). No occupancy hints (R6/7/9 spill).
template<bool GATHER, bool DENSE>
__global__ __launch_bounds__(256)
void gemm_splitk(const float* __restrict__ A, int lda,
                 const float* __restrict__ W0, const float* __restrict__ W1,
                 long long wstride,
                 float* __restrict__ C0, float* __restrict__ C1,
                 float* __restrict__ P0, float* __restrict__ P1,
                 int N, int K,
                 const int* __restrict__ order, const int* __restrict__ offsets,
                 const int* __restrict__ tlist)
{
  const float* W; float* dst;
  int mbase, r1, n0, kb;
  if (DENSE){
    const int bid = (int)(blockIdx.x + 16u*blockIdx.y + 256u*blockIdx.z);  // 0..1023
    const int wf = (bid & 7) * 128 + (bid >> 3);                           // bijective XCD swizzle
    const int ny = wf & 15, mx = (wf >> 4) & 15, zz = wf >> 8;             // zz 0..3
    const int net = zz & 1; kb = zz >> 1;
    mbase = mx * 64; r1 = Bsz; n0 = ny * 64;
    W = net ? W1 : W0;
    dst = kb ? (net ? P1 : P0) : (net ? C1 : C0);
  } else {
    const int bid = (int)(blockIdx.x + 23u*blockIdx.y + 368u*blockIdx.z);  // 0..735
    const int wf = (bid & 7) * 92 + (bid >> 3);                            // bijective (736=92*8)
    kb = wf / 368; const int rem = wf - kb * 368;
    const int i = rem >> 4;
    if (i >= tlist[0]) return;
    const int o = tlist[1 + 2*i];
    mbase = tlist[2 + 2*i];
    r1 = offsets[o + 1];
    n0 = (rem & 15) * 64;
    W = W0 + (long long)o * wstride;
    dst = kb ? P0 : C0;
  }

  __shared__ float lds[8576];   // staging: 4 waves x 1024; reduce: 2 x 4288 (overlaid after K-loop)

  const int tid = threadIdx.x;
  const int wv = tid >> 6, lane = tid & 63;
  const int ty = lane >> 3, tx = lane & 7;
  const int KC = K >> 3, NT = KC >> 3;      // K / (4 waves x 2 kb); 8-k sub-tiles
  const int k0 = (kb * 4 + wv) * KC;
  const int bkr = lane >> 4;                // B: base k-row (0..3)
  const int bnc = (lane & 15) * 4;          // B: column quad

  int grow = mbase + lane;
  int arow = grow < r1 ? grow : mbase;
  if (GATHER) arow = order[arow];
  const float* Ap = A + (long long)arow * lda + k0;
  const float* Wp = W + (long long)k0 * N + n0 + bnc;

  float* myst = lds + wv * 1024;            // [As 8x64 | Bs 8x64]

  float acc[8][8];
#pragma unroll
  for (int i = 0; i < 8; i++)
#pragma unroll
    for (int j = 0; j < 8; j++) acc[i][j] = 0.f;

  float4 a4[2], b4[2];

#define LOADT(it) {                                                          \
    const float* ap = Ap + (it) * 8;                                         \
    a4[0] = *(const float4*)(ap + 0);  a4[1] = *(const float4*)(ap + 4);     \
    const float* wp = Wp + (long long)((it) * 8 + bkr) * N;                  \
    b4[0] = *(const float4*)(wp);                                            \
    b4[1] = *(const float4*)(wp + (long long)4 * N); }

#define STORET() {                                                           \
    float* As = myst;                                                        \
    float* Bs = myst + 512;                                                  \
    _Pragma("unroll")                                                        \
    for (int q = 0; q < 2; q++){                                             \
      As[(q*4 + 0)*64 + lane] = a4[q].x;                                     \
      As[(q*4 + 1)*64 + lane] = a4[q].y;                                     \
      As[(q*4 + 2)*64 + lane] = a4[q].z;                                     \
      As[(q*4 + 3)*64 + lane] = a4[q].w; }                                   \
    _Pragma("unroll")                                                        \
    for (int r = 0; r < 2; r++)                                              \
      *(float4*)(Bs + (bkr + r*4)*64 + bnc) = b4[r]; }

  LOADT(0); STORET(); LOADT(1);
  asm volatile("s_waitcnt lgkmcnt(0)" ::: "memory");

  for (int it = 0; it < NT; ++it){
    const float* As = myst;
    const float* Bs = myst + 512;
#pragma unroll
    for (int kk = 0; kk < 8; ++kk){
      float4 av0 = *(const float4*)(As + kk*64 + ty*8);
      float4 av1 = *(const float4*)(As + kk*64 + ty*8 + 4);
      float4 bv0 = *(const float4*)(Bs + kk*64 + tx*8);
      float4 bv1 = *(const float4*)(Bs + kk*64 + tx*8 + 4);
      float a[8] = {av0.x,av0.y,av0.z,av0.w,av1.x,av1.y,av1.z,av1.w};
      float b[8] = {bv0.x,bv0.y,bv0.z,bv0.w,bv1.x,bv1.y,bv1.z,bv1.w};
#pragma unroll
      for (int i = 0; i < 8; i++)
#pragma unroll
        for (int j = 0; j < 8; j++) acc[i][j] = fmaf(a[i], b[j], acc[i][j]);
    }
    if (it + 1 < NT){
      asm volatile("s_waitcnt lgkmcnt(0)" ::: "memory");  // reads retired before overwrite
      STORET();                                           // (compiler inserts vmcnt for a4/b4)
      if (it + 2 < NT) LOADT(it + 2);
      asm volatile("s_waitcnt lgkmcnt(0)" ::: "memory");  // stores landed before next compute
    }
  }
#undef LOADT
#undef STORET

  // ---- log-tree cross-wave reduce: 4 -> 2 -> 1 (stride 67, proven 0-conflict R10-R15) ----
#define RWRITE(w) { float* r = lds + (w) * 4288 + lane * 67;                 \
    _Pragma("unroll")                                                        \
    for (int i = 0; i < 8; i++)                                              \
      _Pragma("unroll")                                                      \
      for (int j = 0; j < 8; j++) r[i*8 + j] = acc[i][j]; }
#define RADD(w) { const float* r = lds + (w) * 4288 + lane * 67;             \
    _Pragma("unroll")                                                        \
    for (int i = 0; i < 8; i++)                                              \
      _Pragma("unroll")                                                      \
      for (int j = 0; j < 8; j++) acc[i][j] += r[i*8 + j]; }

  __syncthreads();
  if (wv == 2 || wv == 3) RWRITE(wv - 2);
  __syncthreads();
  if (wv < 2)  RADD(wv);
  __syncthreads();
  if (wv == 1) RWRITE(0);
  __syncthreads();
  if (wv == 0){
    RADD(0);
#pragma unroll
    for (int i = 0; i < 8; i++){
      int row = mbase + ty*8 + i;
      if (row < r1){
        float* p = dst + (long long)row * N + n0 + tx*8;
        float4 v0, v1;
        v0.x = acc[i][0]; v0.y = acc[i][1]; v0.z = acc[i][2]; v0.w = acc[i][3];
        v1.x = acc[i][4]; v1.y = acc[i][5]; v1.z = acc[i][6]; v1.w = acc[i][7];
        *(float4*)p = v0; *(float4*)(p + 4) = v1;
      }
    }
  }
#undef RWRITE
#undef RADD
}

// ---------------- fused split-K reduce + bias + relu: C = relu(C + P + bias) ----------------
// DENSE2: grid (1024, 2), z picks net. grouped: grid (1024, 1), per-row expert bias via offsets.
template<bool DENSE2>
__global__ __launch_bounds__(256)
void reduce_relu(float* __restrict__ C0, float* __restrict__ C1,
                 const float* __restrict__ P0, const float* __restrict__ P1,
                 const float* __restrict__ b0, const float* __restrict__ b1,
                 int bstride, const int* __restrict__ offsets, int N)
{
  const int row = blockIdx.x;
  float* C; const float* P; const float* bias;
  if (DENSE2){
    const int z = blockIdx.y;
    C = z ? C1 : C0; P = z ? P1 : P0; bias = z ? b1 : b0;
  } else {
    C = C0; P = P0;
    int o = 0;
#pragma unroll
    for (int i = 1; i < 8; ++i) if (offsets[i] <= row) o = i;
    bias = b0 + o * bstride;
  }
  const int c = threadIdx.x * 4;
  float* cp = C + (long long)row * N + c;
  float4 a  = *(float4*)cp;
  float4 p  = *(const float4*)(P + (long long)row * N + c);
  float4 bb = *(const float4*)(bias + c);
  a.x = fmaxf(a.x + p.x + bb.x, 0.f);
  a.y = fmaxf(a.y + p.y + bb.y, 0.f);
  a.z = fmaxf(a.z + p.z + bb.z, 0.f);
  a.w = fmaxf(a.w + p.w + bb.w, 0.f);
  *(float4*)cp = a;
}

// ---------------- per-row head: opt logits + softmax + argmax + gumbel sel + termination ----------------
__global__ __launch_bounds__(256)
void head_kernel(const float* __restrict__ h1, const float* __restrict__ th,
                 const float* __restrict__ ow2, const float* __restrict__ ob2,
                 const float* __restrict__ tw2, const float* __restrict__ tb2,
                 float* __restrict__ out, int* __restrict__ sel)
{
  const int b = blockIdx.x;
  const int t = threadIdx.x;
  const float* hrow = h1 + b * Hdim;
  const float* trow = th + b * Hdim;

  float acc[8] = {}; float accT = 0.f;
  for (int k = t; k < Hdim; k += 256){
    float hv = hrow[k];
    const float* w = ow2 + k * 8;
#pragma unroll
    for (int o2 = 0; o2 < 8; ++o2) acc[o2] += hv * w[o2];
    accT += trow[k] * tw2[k];
  }
#pragma unroll
  for (int o2 = 0; o2 < 8; ++o2)
    for (int off = 32; off; off >>= 1) acc[o2] += __shfl_down(acc[o2], off);
  for (int off = 32; off; off >>= 1) accT += __shfl_down(accT, off);

  __shared__ float wred[4][9];
  __shared__ float logits[8];
  __shared__ float gum[8];
  const int wave = t >> 6, lane = t & 63;
  if (lane == 0){
#pragma unroll
    for (int o2 = 0; o2 < 8; ++o2) wred[wave][o2] = acc[o2];
    wred[wave][8] = accT;
  }
  __syncthreads();
  if (t < 9){
    float s = wred[0][t] + wred[1][t] + wred[2][t] + wred[3][t];
    if (t < 8) logits[t] = s + ob2[t];
    else       out[OFF_TERM + b] = 1.f / (1.f + expf(-(s + tb2[0])));
  }
  __syncthreads();
  if (t < 8) gum[t] = logits[t] + gumbel_at(b * 8 + t);
  __syncthreads();
  if (t == 0){
    float m = logits[0]; int am = 0;
#pragma unroll
    for (int o2 = 1; o2 < 8; ++o2) if (logits[o2] > m){ m = logits[o2]; am = o2; }
    float p[8]; float s = 0.f;
#pragma unroll
    for (int o2 = 0; o2 < 8; ++o2){ p[o2] = expf(logits[o2] - m); s += p[o2]; }
    float inv = 1.f / s;
#pragma unroll
    for (int o2 = 0; o2 < 8; ++o2) out[b * 8 + o2] = p[o2] * inv;
    out[OFF_OARG + b] = (float)am;
    float gm = gum[0]; int gs = 0;
#pragma unroll
    for (int o2 = 1; o2 < 8; ++o2) if (gum[o2] > gm){ gm = gum[o2]; gs = o2; }
    sel[b] = gs;
  }
}

// ---------------- routing: bucket samples by expert + emit row-tile list ----------------
__global__ void route_kernel(const int* __restrict__ sel, int* __restrict__ order,
                             int* __restrict__ offsets, int* __restrict__ tlist)
{
  __shared__ int cnt[8];
  __shared__ int base[8];
  const int t = threadIdx.x;
  if (t < 8) cnt[t] = 0;
  __syncthreads();
  const int s = sel[t];
  atomicAdd(&cnt[s], 1);
  __syncthreads();
  if (t == 0){
    int a = 0;
    for (int o = 0; o < 8; ++o){ offsets[o] = a; base[o] = a; a += cnt[o]; }
    offsets[8] = a;
    int nt = 0;
    for (int o = 0; o < 8; ++o)
      for (int mb = offsets[o]; mb < offsets[o] + cnt[o]; mb += 64){
        tlist[1 + 2*nt] = o; tlist[2 + 2*nt] = mb; ++nt;
      }
    tlist[0] = nt;
  }
  __syncthreads();
  const int pos = atomicAdd(&base[s], 1);
  order[pos] = t;   // permutation within an expert is nondeterministic; outputs don't depend on it
}

// ---------------- per-row output head: q = h2 @ awo + abo, softmax, argmax ----------------
__global__ __launch_bounds__(256)
void expert_out_kernel(const float* __restrict__ he2, const float* __restrict__ awo,
                       const float* __restrict__ abo,
                       const int* __restrict__ order, const int* __restrict__ offsets,
                       float* __restrict__ out)
{
  const int r = blockIdx.x;
  int o = 0;
#pragma unroll
  for (int i = 1; i < 8; ++i) if (offsets[i] <= r) o = i;
  const int t = threadIdx.x;
  const int a = t & 63, kg = t >> 6;
  const float* hrow = he2 + r * Hdim;
  const float* W = awo + o * Hdim * Aact;
  float acc = 0.f;
  const int k0 = kg * 256;
  for (int k = k0; k < k0 + 256; ++k) acc += hrow[k] * W[k * Aact + a];
  __shared__ float redm[4][64];
  redm[kg][a] = acc;
  __syncthreads();
  if (t < 64){
    float q = redm[0][a] + redm[1][a] + redm[2][a] + redm[3][a] + abo[o * Aact + a];
    float m = q;
#pragma unroll
    for (int off = 32; off; off >>= 1) m = fmaxf(m, __shfl_xor(m, off));
    float e = expf(q - m);
    float s = e;
#pragma unroll
    for (int off = 32; off; off >>= 1) s += __shfl_xor(s, off);
    const int b = order[r];
    out[OFF_ACT + b * Aact + a] = e / s;
    unsigned long long msk = __ballot(q == m);
    if (a == 0) out[OFF_SACT + b] = (float)__builtin_ctzll(msk);
  }
}

extern "C" void kernel_launch(void* const* d_in, const int* in_sizes, int n_in,
                              void* d_out, int out_size, void* d_ws, size_t ws_size,
                              hipStream_t stream)
{
  (void)in_sizes; (void)n_in; (void)out_size; (void)ws_size;
  const float* state = (const float*)d_in[0];
  const float* ow1   = (const float*)d_in[1];
  const float* ob1   = (const float*)d_in[2];
  const float* ow2   = (const float*)d_in[3];
  const float* ob2   = (const float*)d_in[4];
  const float* aw1   = (const float*)d_in[5];
  const float* ab1   = (const float*)d_in[6];
  const float* awh   = (const float*)d_in[7];
  const float* abh   = (const float*)d_in[8];
  const float* awo   = (const float*)d_in[9];
  const float* abo   = (const float*)d_in[10];
  const float* tw1   = (const float*)d_in[11];
  const float* tb1   = (const float*)d_in[12];
  const float* tw2   = (const float*)d_in[13];
  const float* tb2   = (const float*)d_in[14];
  float* out = (float*)d_out;

  float* h1  = (float*)d_ws;            // [1024][1024] opt hidden -> L1 out
  float* h2  = h1 + Bsz * Hdim;         // [1024][1024] term hidden -> L2 out
  float* pd0 = h2 + Bsz * Hdim;         // [1024][1024] kb=1 partial (net0 / L1 / L2)
  float* pd1 = pd0 + Bsz * Hdim;        // [1024][1024] kb=1 partial (net1)
  int* sel     = (int*)(pd1 + Bsz * Hdim);
  int* order   = sel + Bsz;
  int* offsets = order + Bsz;
  int* tlist   = offsets + 9;           // [ntiles | (expert,mbase) * MAXT]

  // 1. dense pair raw sums: kb0 -> {h1,h2}, kb1 -> {pd0,pd1}
  gemm_splitk<false,true><<<dim3(16,16,4), 256, 0, stream>>>(
      state, Din, ow1, tw1, 0, h1, h2, pd0, pd1, Hdim, Din, nullptr, nullptr, nullptr);
  // 2. h1 = relu(h1+pd0+ob1); h2 = relu(h2+pd1+tb1)
  reduce_relu<true><<<dim3(Bsz,2), 256, 0, stream>>>(
      h1, h2, pd0, pd1, ob1, tb1, 0, nullptr, Hdim);
  // 3. heads: opt softmax/argmax, gumbel categorical sel, termination sigmoid
  head_kernel<<<dim3(Bsz), 256, 0, stream>>>(h1, h2, ow2, ob2, tw2, tb2, out, sel);
  // 4. bucket samples by expert + tile list
  route_kernel<<<dim3(1), 1024, 0, stream>>>(sel, order, offsets, tlist);
  // 5. expert L1 raw sums (gather state rows): kb0 -> h1, kb1 -> pd0
  gemm_splitk<true,false><<<dim3(MAXT,16,2), 256, 0, stream>>>(
      state, Din, aw1, nullptr, (long long)Din*Hdim, h1, nullptr, pd0, nullptr,
      Hdim, Din, order, offsets, tlist);
  // 6. h1 = relu(h1+pd0+ab1[o(row)])
  reduce_relu<false><<<dim3(Bsz,1), 256, 0, stream>>>(
      h1, nullptr, pd0, nullptr, ab1, nullptr, Hdim, offsets, Hdim);
  // 7. expert L2 raw sums: kb0 -> h2, kb1 -> pd0
  gemm_splitk<false,false><<<dim3(MAXT,16,2), 256, 0, stream>>>(
      h1, Hdim, awh, nullptr, (long long)Hdim*Hdim, h2, nullptr, pd0, nullptr,
      Hdim, Hdim, nullptr, offsets, tlist);
  // 8. h2 = relu(h2+pd0+abh[o(row)])
  reduce_relu<false><<<dim3(Bsz,1), 256, 0, stream>>>(
      h2, nullptr, pd0, nullptr, abh, nullptr, Hdim, offsets, Hdim);
  // 9. output head: q, action softmax, selected action
  expert_out_kernel<<<dim3(Bsz), 256, 0, stream>>>(h2, awo, abo, order, offsets, out);
}